// Round 18
// baseline (588.418 us; speedup 1.0000x reference)
//
#include <hip/hip_runtime.h>
#include <hip/hip_bf16.h>
#include <cstdint>
#include <cstddef>

constexpr int B_ = 2, SQ_ = 2048, SK_ = 2048, H_ = 32, HK_ = 8, D_ = 128;
constexpr float QSCALE_ = 0.12751874f;           // (1/sqrt(128)) * log2(e)
constexpr float THR_ = 11.5f;                    // 8 nats in log2 units

typedef __attribute__((ext_vector_type(4))) float f32x4;
typedef __attribute__((ext_vector_type(8))) short bf16x8;
typedef __attribute__((ext_vector_type(4))) short bf16x4;

__device__ __forceinline__ unsigned short f2bf(float f) {
  union { float f; uint32_t u; } v; v.f = f;
  uint32_t u = v.u;
  return (unsigned short)((u + 0x7FFFu + ((u >> 16) & 1u)) >> 16);  // RNE
}

__device__ __forceinline__ unsigned short cvt_bf16(float x) {
  __hip_bfloat16 h = __float2bfloat16(x);   // single HW cvt, RNE
  return *reinterpret_cast<unsigned short*>(&h);
}

__device__ __forceinline__ float exp2_fast(float x) {
  float r;
  asm volatile("v_exp_f32 %0, %1" : "=v"(r) : "v"(x));  // v_exp_f32 = 2^x
  return r;
}

__device__ __forceinline__ void gload16(const void* g, void* l) {
  __builtin_amdgcn_global_load_lds((const __attribute__((address_space(1))) void*)g,
                                   (__attribute__((address_space(3))) void*)l, 16, 0, 0);
}

// ---- sk_valid per batch (mask dtype sniffed at runtime)
__global__ void skv_kernel(const void* __restrict__ mask, int* __restrict__ skv_out) {
  const int b = blockIdx.x;
  const int tid = threadIdx.x;
  __shared__ int red[256];
  const uint32_t* mw = (const uint32_t*)mask;
  const uint32_t w0 = mw[0], w1 = mw[1];
  int cnt = 0;
  if (w0 > 1u) {
    const uint8_t* m = (const uint8_t*)mask + (size_t)b * SK_;
    for (int s = tid; s < SK_; s += 256) cnt += (m[s] != 0);
  } else if (w1 == 0u) {
    const uint32_t* m = mw + (size_t)b * SK_ * 2;
    for (int s = tid; s < SK_; s += 256) cnt += (m[2 * s] != 0);
  } else {
    const int* m = (const int*)mask + (size_t)b * SK_;
    for (int s = tid; s < SK_; s += 256) cnt += (m[s] != 0);
  }
  red[tid] = cnt;
  __syncthreads();
  for (int o = 128; o > 0; o >>= 1) {
    if (tid < o) red[tid] += red[tid + o];
    __syncthreads();
  }
  if (tid == 0) skv_out[b] = red[0];
}

// ---- mean of V over all SK keys (uniform-softmax degenerate rows)
__global__ void meanv_kernel(const float* __restrict__ kv, float* __restrict__ meanv) {
  const int blk = blockIdx.x;
  const int chunk = blk & 15;
  const int hk = (blk >> 4) & 7;
  const int b = blk >> 7;
  const int d = threadIdx.x;
  float sum = 0.0f;
  for (int i = 0; i < 128; ++i) {
    const int s = chunk * 128 + i;
    sum += kv[((((size_t)b * SK_ + s) * 2 + 1) * HK_ + hk) * D_ + d];
  }
  atomicAdd(meanv + ((size_t)b * HK_ + hk) * D_ + d, sum * (1.0f / (float)SK_));
}

// ---- K: f32 [b][s][0][hk][d] -> bf16 Kb [b][hk][s][d]
__global__ void convk(const float* __restrict__ kv, unsigned short* __restrict__ Kb) {
  const int b = blockIdx.z, hk = blockIdx.y;
  const int s = blockIdx.x * 16 + (threadIdx.x >> 4);
  const int dc = (threadIdx.x & 15) * 8;
  const float* src = kv + ((((size_t)b * SK_ + s) * 2 + 0) * HK_ + hk) * D_ + dc;
  f32x4 a0 = *(const f32x4*)src;
  f32x4 a1 = *(const f32x4*)(src + 4);
  bf16x8 t;
  t[0] = (short)f2bf(a0[0]); t[1] = (short)f2bf(a0[1]);
  t[2] = (short)f2bf(a0[2]); t[3] = (short)f2bf(a0[3]);
  t[4] = (short)f2bf(a1[0]); t[5] = (short)f2bf(a1[1]);
  t[6] = (short)f2bf(a1[2]); t[7] = (short)f2bf(a1[3]);
  *(bf16x8*)(Kb + ((size_t)(b * HK_ + hk) * SK_ + s) * D_ + dc) = t;
}

// ---- V: f32 [b][s][1][hk][d] -> bf16 VTb [b][hk][d][s] (transposed)
__global__ void convvt(const float* __restrict__ kv, unsigned short* __restrict__ VTb) {
  const int b = blockIdx.z, hk = blockIdx.y;
  const int s0 = blockIdx.x * 64;
  const int d = threadIdx.x & 127;
  const int sg = threadIdx.x >> 7;
  unsigned short vals[32];
#pragma unroll
  for (int i = 0; i < 32; ++i) {
    const int s = s0 + sg * 32 + i;
    vals[i] = f2bf(kv[((((size_t)b * SK_ + s) * 2 + 1) * HK_ + hk) * D_ + d]);
  }
  unsigned short* dst = VTb + ((size_t)(b * HK_ + hk) * D_ + d) * SK_ + s0 + sg * 32;
#pragma unroll
  for (int c = 0; c < 4; ++c) {
    bf16x8 t;
#pragma unroll
    for (int i = 0; i < 8; ++i) t[i] = (short)vals[c * 8 + i];
    *(bf16x8*)(dst + c * 8) = t;
  }
}

// ---- flash attention v18: KVBLK=64, K double-buffered + V single-buffered
//      (48KB LDS -> 3 blocks/CU), launch_bounds(256,3) (reg target ~170),
//      per-rb fused softmax+PV (PV(rb0) MFMA overlaps softmax(rb1) VALU).
__global__ __launch_bounds__(256, 3)
void flash18(const float* __restrict__ q, const unsigned short* __restrict__ Kb,
             const unsigned short* __restrict__ VTb, const int* __restrict__ skv_arr,
             const float* __restrict__ meanv, float* __restrict__ out,
             int* __restrict__ work_ctr) {
  const int tid = threadIdx.x;
  const int w = tid >> 6, l = tid & 63, lg = l >> 4, lr = l & 15;

  __shared__ char smem[49152];
  char* kb0 = smem;
  char* kb1 = smem + 16384;
  char* vb  = smem + 32768;

  const int NITEMS = (SQ_ / 32) * HK_ * B_;  // 1024

  for (;;) {
    if (tid == 0) *(volatile int*)smem = atomicAdd(work_ctr, 1);
    __syncthreads();
    const int r = *(volatile int*)smem;
    __syncthreads();
    if (r >= NITEMS) break;

    const int qt = 63 - (r >> 4);   // heaviest first (LPT)
    const int hk = (r >> 1) & 7;
    const int b = r & 1;
    const int h = hk * 4 + w;       // each wave: one q-head of the GQA group
    const int t0 = qt * 32;
    const int skv = skv_arr[b];

    // Q B-fragments (swapped QK^T), QSCALE = SCALE*log2e folded in.
    bf16x8 qf[2][4];
#pragma unroll
    for (int rb = 0; rb < 2; ++rb) {
      const int trow = t0 + rb * 16 + lr;
      const float* qp = q + (((size_t)b * SQ_ + trow) * H_ + h) * D_;
#pragma unroll
      for (int kk = 0; kk < 4; ++kk) {
        f32x4 a0 = *(const f32x4*)(qp + kk * 32 + lg * 8);
        f32x4 a1 = *(const f32x4*)(qp + kk * 32 + lg * 8 + 4);
        bf16x8 t;
        t[0] = (short)f2bf(a0[0] * QSCALE_); t[1] = (short)f2bf(a0[1] * QSCALE_);
        t[2] = (short)f2bf(a0[2] * QSCALE_); t[3] = (short)f2bf(a0[3] * QSCALE_);
        t[4] = (short)f2bf(a1[0] * QSCALE_); t[5] = (short)f2bf(a1[1] * QSCALE_);
        t[6] = (short)f2bf(a1[2] * QSCALE_); t[7] = (short)f2bf(a1[3] * QSCALE_);
        qf[rb][kk] = t;
      }
    }

    f32x4 acc0[8], acc1[8];
#pragma unroll
    for (int i = 0; i < 8; ++i) { acc0[i] = (f32x4)0.0f; acc1[i] = (f32x4)0.0f; }
    float m_[2], l_[2];  // m in log2 units; l lane-partial
#pragma unroll
    for (int rb = 0; rb < 2; ++rb) { m_[rb] = -1e30f; l_[rb] = 0.0f; }

    int n_allowed = t0 + 31 + skv - SQ_ + 1;
    if (n_allowed > skv) n_allowed = skv;
    const int nt = (n_allowed > 0) ? ((n_allowed + 63) >> 6) : 0;

    const char* kgb = (const char*)Kb + ((size_t)(b * HK_ + hk)) * SK_ * D_ * 2;
    const char* vgb = (const char*)VTb + ((size_t)(b * HK_ + hk)) * (size_t)D_ * SK_ * 2;

    // K tile 16KB (64 keys x 128d, row=key, (row&7)<<4 swizzle), 4 loads/wave.
    auto stage_k = [&](char* kdst, int s0) {
      const char* kt = kgb + (size_t)s0 * 256;
#pragma unroll
      for (int i = 0; i < 4; ++i) {
        const int c8 = w * 4 + i;
        const int beta = c8 * 1024 + l * 16;
        const int row = beta >> 8;
        gload16(kt + (beta ^ ((row & 7) << 4)), kdst + c8 * 1024);
      }
    };
    // V^T tile 16KB (128d x 64 keys, row=d, ((d&7)<<4) swizzle), 4 loads/wave.
    auto stage_v = [&](int s0) {
      const char* vt = vgb + (size_t)s0 * 2;
#pragma unroll
      for (int i = 0; i < 4; ++i) {
        const int c8 = w * 4 + i;
        const int beta = c8 * 1024 + l * 16;
        const int lam = beta ^ (((beta >> 7) & 7) << 4);
        const int d = lam >> 7, keyb = lam & 127;
        gload16(vt + (size_t)d * (SK_ * 2) + keyb, vb + c8 * 1024);
      }
    };

    asm volatile("s_waitcnt vmcnt(0)" ::: "memory");
    if (nt > 0) stage_k(kb0, 0);

    for (int j = 0; j < nt; ++j) {
      char* kcur = (j & 1) ? kb1 : kb0;
      char* knext = (j & 1) ? kb0 : kb1;
      const int s0 = j * 64;

      // vb is free (barrier at end of previous iteration / item-end syncthreads)
      stage_v(s0);
      const bool more = (j + 1 < nt);
      if (more) stage_k(knext, (j + 1) * 64);

      // wait K(j) complete (own), allow V(j) [+K(j+1)] in flight
      if (more) { asm volatile("s_waitcnt vmcnt(8)" ::: "memory"); }
      else      { asm volatile("s_waitcnt vmcnt(4)" ::: "memory"); }
      __builtin_amdgcn_s_barrier();   // K(j) visible to all waves

      // ---- S^T = K Q^T (log2 domain): sc[rb][c][rr], keys s0 + c*16 + lg*4 + rr
      f32x4 sc[2][4];
#pragma unroll
      for (int c = 0; c < 4; ++c) { sc[0][c] = (f32x4)0.0f; sc[1][c] = (f32x4)0.0f; }
      __builtin_amdgcn_s_setprio(1);
#pragma unroll
      for (int c = 0; c < 4; ++c) {
        const int row = c * 16 + lr;
        const int kx = (row & 7) << 4;
#pragma unroll
        for (int kk = 0; kk < 4; ++kk) {
          const int byte = (row << 8) + ((kk * 32 + lg * 8) << 1);
          bf16x8 kf = *(const bf16x8*)(kcur + (byte ^ kx));
          sc[0][c] = __builtin_amdgcn_mfma_f32_16x16x32_bf16(kf, qf[0][kk], sc[0][c], 0, 0, 0);
          sc[1][c] = __builtin_amdgcn_mfma_f32_16x16x32_bf16(kf, qf[1][kk], sc[1][c], 0, 0, 0);
        }
      }
      __builtin_amdgcn_s_setprio(0);

      // wait V(j) complete (own, landed under QK^T), allow K(j+1) in flight
      if (more) { asm volatile("s_waitcnt vmcnt(4)" ::: "memory"); }
      else      { asm volatile("s_waitcnt vmcnt(0)" ::: "memory"); }
      __builtin_amdgcn_s_barrier();   // V(j) visible to all waves

      // ---- per row-block: mask -> defer-max -> softmax -> PV
      const int kbase = s0 + (lg << 2);
#pragma unroll
      for (int rb = 0; rb < 2; ++rb) {
        f32x4* scr = sc[rb];
        f32x4* accr = rb ? acc1 : acc0;

        const int lim_min = t0 + rb * 16 + skv - SQ_;
        if (s0 + 63 > lim_min) {
          const int lim = t0 + rb * 16 + lr + skv - SQ_;
#pragma unroll
          for (int c = 0; c < 4; ++c)
#pragma unroll
            for (int rr = 0; rr < 4; ++rr)
              if (kbase + c * 16 + rr > lim) scr[c][rr] = -1e30f;
        }

        float mx = scr[0][0];
#pragma unroll
        for (int c = 0; c < 4; ++c)
#pragma unroll
          for (int rr = 0; rr < 4; ++rr) mx = fmaxf(mx, scr[c][rr]);
        if (!__all(mx - m_[rb] <= THR_)) {
          float fm = fmaxf(mx, __shfl_xor(mx, 16));
          fm = fmaxf(fm, __shfl_xor(fm, 32));
          const float mn = fmaxf(m_[rb], fm);
          const float al = exp2_fast(m_[rb] - mn);
          m_[rb] = mn;
          l_[rb] *= al;
          float alq[4];
#pragma unroll
          for (int rr = 0; rr < 4; ++rr) alq[rr] = __shfl(al, lg * 4 + rr, 16);
#pragma unroll
          for (int dd = 0; dd < 8; ++dd)
#pragma unroll
            for (int rr = 0; rr < 4; ++rr) accr[dd][rr] *= alq[rr];
        }

        // P = 2^(S-m), packed K=32 A-fragments (slot j<4 = key c2*32+4lg+j,
        // slot j>=4 = key c2*32+16+4lg+(j-4)); lane-partial row-sum.
        bf16x8 pa8[2];
        {
          const float mm = m_[rb];
          float ps = 0.0f;
#pragma unroll
          for (int c = 0; c < 4; ++c) {
            const int c2 = c >> 1, half = (c & 1) * 4;
#pragma unroll
            for (int rr = 0; rr < 4; ++rr) {
              const float pv = exp2_fast(scr[c][rr] - mm);
              ps += pv;
              pa8[c2][half + rr] = (short)cvt_bf16(pv);
            }
          }
          l_[rb] += ps;
        }

        // O += P V: one true K=32 MFMA per (dd, c2)
        __builtin_amdgcn_s_setprio(1);
#pragma unroll
        for (int dd = 0; dd < 8; ++dd) {
          const int d = dd * 16 + lr;
          const int swz = (d & 7) << 4;
#pragma unroll
          for (int c2 = 0; c2 < 2; ++c2) {
            const int base = d * 128 + c2 * 64 + lg * 8;
            bf16x4 vlo = *(const bf16x4*)(vb + (base ^ swz));
            bf16x4 vhi = *(const bf16x4*)(vb + ((base + 32) ^ swz));
            bf16x8 b8 = {vlo[0], vlo[1], vlo[2], vlo[3], vhi[0], vhi[1], vhi[2], vhi[3]};
            accr[dd] = __builtin_amdgcn_mfma_f32_16x16x32_bf16(pa8[c2], b8, accr[dd], 0, 0, 0);
          }
        }
        __builtin_amdgcn_s_setprio(0);
      }

      asm volatile("" ::: "memory");
      __builtin_amdgcn_s_barrier();   // all reads of vb & kcur done -> reusable
    }

    // ---- epilogue: reduce lane-partial l_, normalize / meanv splat
    const float* mp = meanv + ((size_t)(b * HK_ + hk)) * D_;
#pragma unroll
    for (int rb = 0; rb < 2; ++rb) {
      const f32x4* acc = rb ? acc1 : acc0;
      float lsum = l_[rb] + __shfl_xor(l_[rb], 16);
      lsum += __shfl_xor(lsum, 32);
#pragma unroll
      for (int rr = 0; rr < 4; ++rr) {
        const float lq = __shfl(lsum, lg * 4 + rr, 16);
        const int t_r = t0 + rb * 16 + lg * 4 + rr;
        const bool deg = (t_r + skv - SQ_) < 0;
        const float inv = 1.0f / lq;
        float* op = out + (((size_t)b * SQ_ + t_r) * H_ + h) * D_;
#pragma unroll
        for (int dd = 0; dd < 8; ++dd) {
          const int d = dd * 16 + lr;
          op[d] = deg ? mp[d] : acc[dd][rr] * inv;
        }
      }
    }
    __syncthreads();  // all waves done with LDS before next item's broadcast
  }
}

extern "C" void kernel_launch(void* const* d_in, const int* in_sizes, int n_in,
                              void* d_out, int out_size, void* d_ws, size_t ws_size,
                              hipStream_t stream) {
  const float* q = (const float*)d_in[0];
  const float* kv = (const float*)d_in[1];
  const void* mask = d_in[2];
  float* out = (float*)d_out;

  const size_t KB_OFF = 0;
  const size_t VT_OFF = 8ull * 1024 * 1024;
  const size_t MV_OFF = 16ull * 1024 * 1024;
  unsigned short* Kb = (unsigned short*)((char*)d_ws + KB_OFF);
  unsigned short* VTb = (unsigned short*)((char*)d_ws + VT_OFF);
  float* meanv = (float*)((char*)d_ws + MV_OFF);
  int* skv = (int*)((char*)d_ws + MV_OFF + 8192);
  int* work_ctr = (int*)((char*)d_ws + MV_OFF + 8192 + 64);

  hipMemsetAsync((char*)d_ws + MV_OFF, 0, 8192 + 128, stream);
  skv_kernel<<<B_, 256, 0, stream>>>(mask, skv);
  convk<<<dim3(SK_ / 16, HK_, B_), 256, 0, stream>>>(kv, Kb);
  convvt<<<dim3(SK_ / 64, HK_, B_), 256, 0, stream>>>(kv, VTb);
  meanv_kernel<<<B_ * HK_ * 16, 128, 0, stream>>>(kv, meanv);
  flash18<<<dim3(768), 256, 0, stream>>>(q, Kb, VTb, skv, meanv, out, work_ctr);
}

// Round 19
// 423.204 us; speedup vs baseline: 1.3904x; 1.3904x over previous
//
#include <hip/hip_runtime.h>
#include <hip/hip_bf16.h>
#include <cstdint>
#include <cstddef>

constexpr int B_ = 2, SQ_ = 2048, SK_ = 2048, H_ = 32, HK_ = 8, D_ = 128;
constexpr float QSCALE_ = 0.12751874f;           // (1/sqrt(128)) * log2(e)
constexpr float THR_ = 11.5f;                    // 8 nats in log2 units

typedef __attribute__((ext_vector_type(4))) float f32x4;
typedef __attribute__((ext_vector_type(8))) short bf16x8;
typedef __attribute__((ext_vector_type(4))) short bf16x4;

__device__ __forceinline__ unsigned short f2bf(float f) {
  union { float f; uint32_t u; } v; v.f = f;
  uint32_t u = v.u;
  return (unsigned short)((u + 0x7FFFu + ((u >> 16) & 1u)) >> 16);  // RNE
}

__device__ __forceinline__ unsigned short cvt_bf16(float x) {
  __hip_bfloat16 h = __float2bfloat16(x);   // single HW cvt, RNE
  return *reinterpret_cast<unsigned short*>(&h);
}

__device__ __forceinline__ float exp2_fast(float x) {
  float r;
  asm volatile("v_exp_f32 %0, %1" : "=v"(r) : "v"(x));  // v_exp_f32 = 2^x
  return r;
}

__device__ __forceinline__ void gload16(const void* g, void* l) {
  __builtin_amdgcn_global_load_lds((const __attribute__((address_space(1))) void*)g,
                                   (__attribute__((address_space(3))) void*)l, 16, 0, 0);
}

// ---- sk_valid per batch (mask dtype sniffed at runtime)
__global__ void skv_kernel(const void* __restrict__ mask, int* __restrict__ skv_out) {
  const int b = blockIdx.x;
  const int tid = threadIdx.x;
  __shared__ int red[256];
  const uint32_t* mw = (const uint32_t*)mask;
  const uint32_t w0 = mw[0], w1 = mw[1];
  int cnt = 0;
  if (w0 > 1u) {
    const uint8_t* m = (const uint8_t*)mask + (size_t)b * SK_;
    for (int s = tid; s < SK_; s += 256) cnt += (m[s] != 0);
  } else if (w1 == 0u) {
    const uint32_t* m = mw + (size_t)b * SK_ * 2;
    for (int s = tid; s < SK_; s += 256) cnt += (m[2 * s] != 0);
  } else {
    const int* m = (const int*)mask + (size_t)b * SK_;
    for (int s = tid; s < SK_; s += 256) cnt += (m[s] != 0);
  }
  red[tid] = cnt;
  __syncthreads();
  for (int o = 128; o > 0; o >>= 1) {
    if (tid < o) red[tid] += red[tid + o];
    __syncthreads();
  }
  if (tid == 0) skv_out[b] = red[0];
}

// ---- mean of V over all SK keys (uniform-softmax degenerate rows)
__global__ void meanv_kernel(const float* __restrict__ kv, float* __restrict__ meanv) {
  const int blk = blockIdx.x;
  const int chunk = blk & 15;
  const int hk = (blk >> 4) & 7;
  const int b = blk >> 7;
  const int d = threadIdx.x;
  float sum = 0.0f;
  for (int i = 0; i < 128; ++i) {
    const int s = chunk * 128 + i;
    sum += kv[((((size_t)b * SK_ + s) * 2 + 1) * HK_ + hk) * D_ + d];
  }
  atomicAdd(meanv + ((size_t)b * HK_ + hk) * D_ + d, sum * (1.0f / (float)SK_));
}

// ---- K: f32 [b][s][0][hk][d] -> bf16 Kb [b][hk][s][d]
__global__ void convk(const float* __restrict__ kv, unsigned short* __restrict__ Kb) {
  const int b = blockIdx.z, hk = blockIdx.y;
  const int s = blockIdx.x * 16 + (threadIdx.x >> 4);
  const int dc = (threadIdx.x & 15) * 8;
  const float* src = kv + ((((size_t)b * SK_ + s) * 2 + 0) * HK_ + hk) * D_ + dc;
  f32x4 a0 = *(const f32x4*)src;
  f32x4 a1 = *(const f32x4*)(src + 4);
  bf16x8 t;
  t[0] = (short)f2bf(a0[0]); t[1] = (short)f2bf(a0[1]);
  t[2] = (short)f2bf(a0[2]); t[3] = (short)f2bf(a0[3]);
  t[4] = (short)f2bf(a1[0]); t[5] = (short)f2bf(a1[1]);
  t[6] = (short)f2bf(a1[2]); t[7] = (short)f2bf(a1[3]);
  *(bf16x8*)(Kb + ((size_t)(b * HK_ + hk) * SK_ + s) * D_ + dc) = t;
}

// ---- V: f32 [b][s][1][hk][d] -> bf16 VTb [b][hk][d][s] (transposed)
__global__ void convvt(const float* __restrict__ kv, unsigned short* __restrict__ VTb) {
  const int b = blockIdx.z, hk = blockIdx.y;
  const int s0 = blockIdx.x * 64;
  const int d = threadIdx.x & 127;
  const int sg = threadIdx.x >> 7;
  unsigned short vals[32];
#pragma unroll
  for (int i = 0; i < 32; ++i) {
    const int s = s0 + sg * 32 + i;
    vals[i] = f2bf(kv[((((size_t)b * SK_ + s) * 2 + 1) * HK_ + hk) * D_ + d]);
  }
  unsigned short* dst = VTb + ((size_t)(b * HK_ + hk) * D_ + d) * SK_ + s0 + sg * 32;
#pragma unroll
  for (int c = 0; c < 4; ++c) {
    bf16x8 t;
#pragma unroll
    for (int i = 0; i < 8; ++i) t[i] = (short)vals[c * 8 + i];
    *(bf16x8*)(dst + c * 8) = t;
  }
}

// ---- flash attention v19: KVBLK=64 staging (K dbuf + V single, 48KB LDS,
//      3 blocks/CU), compute split into two 32-key halves so only sc[2][2]
//      (16 regs) is live at a time -> peak live ~150 < 170 (no spill at
//      launch_bounds(256,3), 3 waves/SIMD).
__global__ __launch_bounds__(256, 3)
void flash19(const float* __restrict__ q, const unsigned short* __restrict__ Kb,
             const unsigned short* __restrict__ VTb, const int* __restrict__ skv_arr,
             const float* __restrict__ meanv, float* __restrict__ out,
             int* __restrict__ work_ctr) {
  const int tid = threadIdx.x;
  const int w = tid >> 6, l = tid & 63, lg = l >> 4, lr = l & 15;

  __shared__ char smem[49152];
  char* kb0 = smem;
  char* kb1 = smem + 16384;
  char* vb  = smem + 32768;

  const int NITEMS = (SQ_ / 32) * HK_ * B_;  // 1024

  for (;;) {
    if (tid == 0) *(volatile int*)smem = atomicAdd(work_ctr, 1);
    __syncthreads();
    const int r = *(volatile int*)smem;
    __syncthreads();
    if (r >= NITEMS) break;

    const int qt = 63 - (r >> 4);   // heaviest first (LPT)
    const int hk = (r >> 1) & 7;
    const int b = r & 1;
    const int h = hk * 4 + w;       // each wave: one q-head of the GQA group
    const int t0 = qt * 32;
    const int skv = skv_arr[b];

    // Q B-fragments (swapped QK^T), QSCALE = SCALE*log2e folded in.
    bf16x8 qf[2][4];
#pragma unroll
    for (int rb = 0; rb < 2; ++rb) {
      const int trow = t0 + rb * 16 + lr;
      const float* qp = q + (((size_t)b * SQ_ + trow) * H_ + h) * D_;
#pragma unroll
      for (int kk = 0; kk < 4; ++kk) {
        f32x4 a0 = *(const f32x4*)(qp + kk * 32 + lg * 8);
        f32x4 a1 = *(const f32x4*)(qp + kk * 32 + lg * 8 + 4);
        bf16x8 t;
        t[0] = (short)f2bf(a0[0] * QSCALE_); t[1] = (short)f2bf(a0[1] * QSCALE_);
        t[2] = (short)f2bf(a0[2] * QSCALE_); t[3] = (short)f2bf(a0[3] * QSCALE_);
        t[4] = (short)f2bf(a1[0] * QSCALE_); t[5] = (short)f2bf(a1[1] * QSCALE_);
        t[6] = (short)f2bf(a1[2] * QSCALE_); t[7] = (short)f2bf(a1[3] * QSCALE_);
        qf[rb][kk] = t;
      }
    }

    f32x4 acc0[8], acc1[8];
#pragma unroll
    for (int i = 0; i < 8; ++i) { acc0[i] = (f32x4)0.0f; acc1[i] = (f32x4)0.0f; }
    float m_[2], l_[2];  // m in log2 units; l lane-partial
#pragma unroll
    for (int rb = 0; rb < 2; ++rb) { m_[rb] = -1e30f; l_[rb] = 0.0f; }

    int n_allowed = t0 + 31 + skv - SQ_ + 1;
    if (n_allowed > skv) n_allowed = skv;
    const int nt = (n_allowed > 0) ? ((n_allowed + 63) >> 6) : 0;

    const char* kgb = (const char*)Kb + ((size_t)(b * HK_ + hk)) * SK_ * D_ * 2;
    const char* vgb = (const char*)VTb + ((size_t)(b * HK_ + hk)) * (size_t)D_ * SK_ * 2;

    // K tile 16KB (64 keys x 128d, row=key, (row&7)<<4 swizzle), 4 loads/wave.
    auto stage_k = [&](char* kdst, int s0) {
      const char* kt = kgb + (size_t)s0 * 256;
#pragma unroll
      for (int i = 0; i < 4; ++i) {
        const int c8 = w * 4 + i;
        const int beta = c8 * 1024 + l * 16;
        const int row = beta >> 8;
        gload16(kt + (beta ^ ((row & 7) << 4)), kdst + c8 * 1024);
      }
    };
    // V^T tile 16KB (128d x 64 keys, row=d, ((d&7)<<4) swizzle), 4 loads/wave.
    auto stage_v = [&](int s0) {
      const char* vt = vgb + (size_t)s0 * 2;
#pragma unroll
      for (int i = 0; i < 4; ++i) {
        const int c8 = w * 4 + i;
        const int beta = c8 * 1024 + l * 16;
        const int lam = beta ^ (((beta >> 7) & 7) << 4);
        const int d = lam >> 7, keyb = lam & 127;
        gload16(vt + (size_t)d * (SK_ * 2) + keyb, vb + c8 * 1024);
      }
    };

    asm volatile("s_waitcnt vmcnt(0)" ::: "memory");
    if (nt > 0) stage_k(kb0, 0);

    for (int j = 0; j < nt; ++j) {
      char* kcur = (j & 1) ? kb1 : kb0;
      char* knext = (j & 1) ? kb0 : kb1;
      const int s0 = j * 64;

      // vb free (end-of-previous-iteration barrier); issue V(j) then K(j+1)
      stage_v(s0);
      const bool more = (j + 1 < nt);
      if (more) stage_k(knext, (j + 1) * 64);

      // wait K(j) (oldest 4); leave V(j) [+K(j+1)] in flight
      if (more) { asm volatile("s_waitcnt vmcnt(8)" ::: "memory"); }
      else      { asm volatile("s_waitcnt vmcnt(4)" ::: "memory"); }
      __builtin_amdgcn_s_barrier();   // K(j) visible to all waves

      // ---- two 32-key halves; only sc[2][2] live at a time
#pragma unroll
      for (int hh = 0; hh < 2; ++hh) {
        // S^T = K Q^T (log2 domain): keys s0 + hh*32 + c*16 + lg*4 + rr
        f32x4 sc[2][2];
        sc[0][0] = (f32x4)0.0f; sc[0][1] = (f32x4)0.0f;
        sc[1][0] = (f32x4)0.0f; sc[1][1] = (f32x4)0.0f;
        __builtin_amdgcn_s_setprio(1);
#pragma unroll
        for (int c = 0; c < 2; ++c) {
          const int row = hh * 32 + c * 16 + lr;
          const int kx = (row & 7) << 4;
#pragma unroll
          for (int kk = 0; kk < 4; ++kk) {
            const int byte = (row << 8) + ((kk * 32 + lg * 8) << 1);
            bf16x8 kf = *(const bf16x8*)(kcur + (byte ^ kx));
            sc[0][c] = __builtin_amdgcn_mfma_f32_16x16x32_bf16(kf, qf[0][kk], sc[0][c], 0, 0, 0);
            sc[1][c] = __builtin_amdgcn_mfma_f32_16x16x32_bf16(kf, qf[1][kk], sc[1][c], 0, 0, 0);
          }
        }
        __builtin_amdgcn_s_setprio(0);

        // after half0's QK^T: V(j) has landed under it -> wait + barrier once
        if (hh == 0) {
          if (more) { asm volatile("s_waitcnt vmcnt(4)" ::: "memory"); }
          else      { asm volatile("s_waitcnt vmcnt(0)" ::: "memory"); }
          __builtin_amdgcn_s_barrier();   // V(j) visible to all waves
        }

        // ---- per row-block: mask -> defer-max -> softmax -> PV (fused)
        const int kbase = s0 + hh * 32 + (lg << 2);
#pragma unroll
        for (int rb = 0; rb < 2; ++rb) {
          f32x4* scr = sc[rb];
          f32x4* accr = rb ? acc1 : acc0;

          const int lim_min = t0 + rb * 16 + skv - SQ_;
          if (s0 + hh * 32 + 31 > lim_min) {
            const int lim = t0 + rb * 16 + lr + skv - SQ_;
#pragma unroll
            for (int c = 0; c < 2; ++c)
#pragma unroll
              for (int rr = 0; rr < 4; ++rr)
                if (kbase + c * 16 + rr > lim) scr[c][rr] = -1e30f;
          }

          float mx = scr[0][0];
#pragma unroll
          for (int c = 0; c < 2; ++c)
#pragma unroll
            for (int rr = 0; rr < 4; ++rr) mx = fmaxf(mx, scr[c][rr]);
          if (!__all(mx - m_[rb] <= THR_)) {
            float fm = fmaxf(mx, __shfl_xor(mx, 16));
            fm = fmaxf(fm, __shfl_xor(fm, 32));
            const float mn = fmaxf(m_[rb], fm);
            const float al = exp2_fast(m_[rb] - mn);
            m_[rb] = mn;
            l_[rb] *= al;
            float alq[4];
#pragma unroll
            for (int rr = 0; rr < 4; ++rr) alq[rr] = __shfl(al, lg * 4 + rr, 16);
#pragma unroll
            for (int dd = 0; dd < 8; ++dd)
#pragma unroll
              for (int rr = 0; rr < 4; ++rr) accr[dd][rr] *= alq[rr];
          }

          // P = 2^(S-m): packed K=32 A-fragment (c=0 -> slots 0-3, c=1 -> 4-7)
          bf16x8 pa8;
          {
            const float mm = m_[rb];
            float ps = 0.0f;
#pragma unroll
            for (int c = 0; c < 2; ++c) {
              const int half = c * 4;
#pragma unroll
              for (int rr = 0; rr < 4; ++rr) {
                const float pv = exp2_fast(scr[c][rr] - mm);
                ps += pv;
                pa8[half + rr] = (short)cvt_bf16(pv);
              }
            }
            l_[rb] += ps;
          }

          // O += P V: one true K=32 MFMA per dd over this half's 32 keys
          __builtin_amdgcn_s_setprio(1);
#pragma unroll
          for (int dd = 0; dd < 8; ++dd) {
            const int d = dd * 16 + lr;
            const int swz = (d & 7) << 4;
            const int base = d * 128 + hh * 64 + lg * 8;
            bf16x4 vlo = *(const bf16x4*)(vb + (base ^ swz));
            bf16x4 vhi = *(const bf16x4*)(vb + ((base + 32) ^ swz));
            bf16x8 b8 = {vlo[0], vlo[1], vlo[2], vlo[3], vhi[0], vhi[1], vhi[2], vhi[3]};
            accr[dd] = __builtin_amdgcn_mfma_f32_16x16x32_bf16(pa8, b8, accr[dd], 0, 0, 0);
          }
          __builtin_amdgcn_s_setprio(0);
        }
      }

      asm volatile("" ::: "memory");
      __builtin_amdgcn_s_barrier();   // all reads of vb & kcur done -> reusable
    }

    // ---- epilogue: reduce lane-partial l_, normalize / meanv splat
    const float* mp = meanv + ((size_t)(b * HK_ + hk)) * D_;
#pragma unroll
    for (int rb = 0; rb < 2; ++rb) {
      const f32x4* acc = rb ? acc1 : acc0;
      float lsum = l_[rb] + __shfl_xor(l_[rb], 16);
      lsum += __shfl_xor(lsum, 32);
#pragma unroll
      for (int rr = 0; rr < 4; ++rr) {
        const float lq = __shfl(lsum, lg * 4 + rr, 16);
        const int t_r = t0 + rb * 16 + lg * 4 + rr;
        const bool deg = (t_r + skv - SQ_) < 0;
        const float inv = 1.0f / lq;
        float* op = out + (((size_t)b * SQ_ + t_r) * H_ + h) * D_;
#pragma unroll
        for (int dd = 0; dd < 8; ++dd) {
          const int d = dd * 16 + lr;
          op[d] = deg ? mp[d] : acc[dd][rr] * inv;
        }
      }
    }
    __syncthreads();  // all waves done with LDS before next item's broadcast
  }
}

extern "C" void kernel_launch(void* const* d_in, const int* in_sizes, int n_in,
                              void* d_out, int out_size, void* d_ws, size_t ws_size,
                              hipStream_t stream) {
  const float* q = (const float*)d_in[0];
  const float* kv = (const float*)d_in[1];
  const void* mask = d_in[2];
  float* out = (float*)d_out;

  const size_t KB_OFF = 0;
  const size_t VT_OFF = 8ull * 1024 * 1024;
  const size_t MV_OFF = 16ull * 1024 * 1024;
  unsigned short* Kb = (unsigned short*)((char*)d_ws + KB_OFF);
  unsigned short* VTb = (unsigned short*)((char*)d_ws + VT_OFF);
  float* meanv = (float*)((char*)d_ws + MV_OFF);
  int* skv = (int*)((char*)d_ws + MV_OFF + 8192);
  int* work_ctr = (int*)((char*)d_ws + MV_OFF + 8192 + 64);

  hipMemsetAsync((char*)d_ws + MV_OFF, 0, 8192 + 128, stream);
  skv_kernel<<<B_, 256, 0, stream>>>(mask, skv);
  convk<<<dim3(SK_ / 16, HK_, B_), 256, 0, stream>>>(kv, Kb);
  convvt<<<dim3(SK_ / 64, HK_, B_), 256, 0, stream>>>(kv, VTb);
  meanv_kernel<<<B_ * HK_ * 16, 128, 0, stream>>>(kv, meanv);
  flash19<<<dim3(768), 256, 0, stream>>>(q, Kb, VTb, skv, meanv, out, work_ctr);
}

// Round 20
// 151.798 us; speedup vs baseline: 3.8763x; 2.7879x over previous
//
#include <hip/hip_runtime.h>
#include <hip/hip_bf16.h>
#include <cstdint>
#include <cstddef>

constexpr int B_ = 2, SQ_ = 2048, SK_ = 2048, H_ = 32, HK_ = 8, D_ = 128;
constexpr float QSCALE_ = 0.12751874f;           // (1/sqrt(128)) * log2(e)
constexpr float THR_ = 11.5f;                    // 8 nats in log2 units

typedef __attribute__((ext_vector_type(4))) float f32x4;
typedef __attribute__((ext_vector_type(8))) short bf16x8;
typedef __attribute__((ext_vector_type(4))) short bf16x4;

__device__ __forceinline__ unsigned short f2bf(float f) {
  union { float f; uint32_t u; } v; v.f = f;
  uint32_t u = v.u;
  return (unsigned short)((u + 0x7FFFu + ((u >> 16) & 1u)) >> 16);  // RNE
}

__device__ __forceinline__ unsigned short cvt_bf16(float x) {
  __hip_bfloat16 h = __float2bfloat16(x);   // single HW cvt, RNE
  return *reinterpret_cast<unsigned short*>(&h);
}

__device__ __forceinline__ float exp2_fast(float x) {
  float r;
  asm volatile("v_exp_f32 %0, %1" : "=v"(r) : "v"(x));  // v_exp_f32 = 2^x
  return r;
}

__device__ __forceinline__ void gload16(const void* g, void* l) {
  __builtin_amdgcn_global_load_lds((const __attribute__((address_space(1))) void*)g,
                                   (__attribute__((address_space(3))) void*)l, 16, 0, 0);
}

// ---- sk_valid per batch (mask dtype sniffed at runtime)
__global__ void skv_kernel(const void* __restrict__ mask, int* __restrict__ skv_out) {
  const int b = blockIdx.x;
  const int tid = threadIdx.x;
  __shared__ int red[256];
  const uint32_t* mw = (const uint32_t*)mask;
  const uint32_t w0 = mw[0], w1 = mw[1];
  int cnt = 0;
  if (w0 > 1u) {
    const uint8_t* m = (const uint8_t*)mask + (size_t)b * SK_;
    for (int s = tid; s < SK_; s += 256) cnt += (m[s] != 0);
  } else if (w1 == 0u) {
    const uint32_t* m = mw + (size_t)b * SK_ * 2;
    for (int s = tid; s < SK_; s += 256) cnt += (m[2 * s] != 0);
  } else {
    const int* m = (const int*)mask + (size_t)b * SK_;
    for (int s = tid; s < SK_; s += 256) cnt += (m[s] != 0);
  }
  red[tid] = cnt;
  __syncthreads();
  for (int o = 128; o > 0; o >>= 1) {
    if (tid < o) red[tid] += red[tid + o];
    __syncthreads();
  }
  if (tid == 0) skv_out[b] = red[0];
}

// ---- K: f32 [b][s][0][hk][d] -> bf16 Kb [b][hk][s][d]
__global__ void convk(const float* __restrict__ kv, unsigned short* __restrict__ Kb) {
  const int b = blockIdx.z, hk = blockIdx.y;
  const int s = blockIdx.x * 16 + (threadIdx.x >> 4);
  const int dc = (threadIdx.x & 15) * 8;
  const float* src = kv + ((((size_t)b * SK_ + s) * 2 + 0) * HK_ + hk) * D_ + dc;
  f32x4 a0 = *(const f32x4*)src;
  f32x4 a1 = *(const f32x4*)(src + 4);
  bf16x8 t;
  t[0] = (short)f2bf(a0[0]); t[1] = (short)f2bf(a0[1]);
  t[2] = (short)f2bf(a0[2]); t[3] = (short)f2bf(a0[3]);
  t[4] = (short)f2bf(a1[0]); t[5] = (short)f2bf(a1[1]);
  t[6] = (short)f2bf(a1[2]); t[7] = (short)f2bf(a1[3]);
  *(bf16x8*)(Kb + ((size_t)(b * HK_ + hk) * SK_ + s) * D_ + dc) = t;
}

// ---- V: f32 [b][s][1][hk][d] -> bf16 VTb [b][hk][d][s] (transposed),
//      FUSED with meanv accumulation (one atomicAdd per thread).
__global__ void convvt(const float* __restrict__ kv, unsigned short* __restrict__ VTb,
                       float* __restrict__ meanv) {
  const int b = blockIdx.z, hk = blockIdx.y;
  const int s0 = blockIdx.x * 64;
  const int d = threadIdx.x & 127;
  const int sg = threadIdx.x >> 7;
  unsigned short vals[32];
  float vsum = 0.0f;
#pragma unroll
  for (int i = 0; i < 32; ++i) {
    const int s = s0 + sg * 32 + i;
    const float v = kv[((((size_t)b * SK_ + s) * 2 + 1) * HK_ + hk) * D_ + d];
    vsum += v;
    vals[i] = f2bf(v);
  }
  unsigned short* dst = VTb + ((size_t)(b * HK_ + hk) * D_ + d) * SK_ + s0 + sg * 32;
#pragma unroll
  for (int c = 0; c < 4; ++c) {
    bf16x8 t;
#pragma unroll
    for (int i = 0; i < 8; ++i) t[i] = (short)vals[c * 8 + i];
    *(bf16x8*)(dst + c * 8) = t;
  }
  atomicAdd(meanv + ((size_t)b * HK_ + hk) * D_ + d, vsum * (1.0f / (float)SK_));
}

// ---- flash attention v20 == v15 (verified best): KVBLK=64 K+V double-buffered
//      (64KB LDS, launch_bounds(256,2)), swapped QK^T, log2-domain softmax,
//      lane-local defer-max, lane-partial l, in-register P packed into true
//      K=32 PV MFMAs, GQA 4-head KV sharing, LPT work queue.
__global__ __launch_bounds__(256, 2)
void flash20(const float* __restrict__ q, const unsigned short* __restrict__ Kb,
             const unsigned short* __restrict__ VTb, const int* __restrict__ skv_arr,
             const float* __restrict__ meanv, float* __restrict__ out,
             int* __restrict__ work_ctr) {
  const int tid = threadIdx.x;
  const int w = tid >> 6, l = tid & 63, lg = l >> 4, lr = l & 15;

  __shared__ char smem[65536];
  char* kc0 = smem;          char* vc0 = smem + 16384;
  char* kn0 = smem + 32768;  char* vn0 = smem + 49152;

  const int NITEMS = (SQ_ / 32) * HK_ * B_;  // 1024

  for (;;) {
    if (tid == 0) *(volatile int*)smem = atomicAdd(work_ctr, 1);
    __syncthreads();
    const int r = *(volatile int*)smem;
    __syncthreads();
    if (r >= NITEMS) break;

    const int qt = 63 - (r >> 4);   // heaviest first (LPT)
    const int hk = (r >> 1) & 7;
    const int b = r & 1;
    const int h = hk * 4 + w;       // each wave: one q-head of the GQA group
    const int t0 = qt * 32;
    const int skv = skv_arr[b];

    char* kc = kc0; char* kn = kn0; char* vc = vc0; char* vn = vn0;

    // Q B-fragments (swapped QK^T), QSCALE = SCALE*log2e folded in.
    bf16x8 qf[2][4];
#pragma unroll
    for (int rb = 0; rb < 2; ++rb) {
      const int trow = t0 + rb * 16 + lr;
      const float* qp = q + (((size_t)b * SQ_ + trow) * H_ + h) * D_;
#pragma unroll
      for (int kk = 0; kk < 4; ++kk) {
        f32x4 a0 = *(const f32x4*)(qp + kk * 32 + lg * 8);
        f32x4 a1 = *(const f32x4*)(qp + kk * 32 + lg * 8 + 4);
        bf16x8 t;
        t[0] = (short)f2bf(a0[0] * QSCALE_); t[1] = (short)f2bf(a0[1] * QSCALE_);
        t[2] = (short)f2bf(a0[2] * QSCALE_); t[3] = (short)f2bf(a0[3] * QSCALE_);
        t[4] = (short)f2bf(a1[0] * QSCALE_); t[5] = (short)f2bf(a1[1] * QSCALE_);
        t[6] = (short)f2bf(a1[2] * QSCALE_); t[7] = (short)f2bf(a1[3] * QSCALE_);
        qf[rb][kk] = t;
      }
    }

    f32x4 acc0[8], acc1[8];
#pragma unroll
    for (int i = 0; i < 8; ++i) { acc0[i] = (f32x4)0.0f; acc1[i] = (f32x4)0.0f; }
    float m_[2], l_[2];  // m in log2 units; l lane-partial
#pragma unroll
    for (int rb = 0; rb < 2; ++rb) { m_[rb] = -1e30f; l_[rb] = 0.0f; }

    int n_allowed = t0 + 31 + skv - SQ_ + 1;
    if (n_allowed > skv) n_allowed = skv;
    const int nt = (n_allowed > 0) ? ((n_allowed + 63) >> 6) : 0;

    const char* kgb = (const char*)Kb + ((size_t)(b * HK_ + hk)) * SK_ * D_ * 2;
    const char* vgb = (const char*)VTb + ((size_t)(b * HK_ + hk)) * (size_t)D_ * SK_ * 2;

    auto stage = [&](char* kdst, char* vdst, int s0) {
      const char* kt = kgb + (size_t)s0 * 256;
#pragma unroll
      for (int i = 0; i < 4; ++i) {
        const int c8 = w * 4 + i;
        const int beta = c8 * 1024 + l * 16;
        const int row = beta >> 8;
        gload16(kt + (beta ^ ((row & 7) << 4)), kdst + c8 * 1024);
      }
      const char* vt = vgb + (size_t)s0 * 2;
#pragma unroll
      for (int i = 0; i < 4; ++i) {
        const int c8 = w * 4 + i;
        const int beta = c8 * 1024 + l * 16;
        const int lam = beta ^ (((beta >> 7) & 7) << 4);
        const int d = lam >> 7, keyb = lam & 127;
        gload16(vt + (size_t)d * (SK_ * 2) + keyb, vdst + c8 * 1024);
      }
    };

    asm volatile("s_waitcnt vmcnt(0)" ::: "memory");
    if (nt > 0) stage(kc, vc, 0);

    for (int j = 0; j < nt; ++j) {
      if (j + 1 < nt) {
        stage(kn, vn, (j + 1) * 64);
        asm volatile("s_waitcnt vmcnt(8)" ::: "memory");
      } else {
        asm volatile("s_waitcnt vmcnt(0)" ::: "memory");
      }
      __builtin_amdgcn_s_barrier();

      const int s0 = j * 64;
      // ---- S^T = K Q^T (log2 domain): sc[rb][c][rr]
      f32x4 sc[2][4];
#pragma unroll
      for (int c = 0; c < 4; ++c) { sc[0][c] = (f32x4)0.0f; sc[1][c] = (f32x4)0.0f; }
      __builtin_amdgcn_s_setprio(1);
#pragma unroll
      for (int c = 0; c < 4; ++c) {
        const int row = c * 16 + lr;
        const int kx = (row & 7) << 4;
#pragma unroll
        for (int kk = 0; kk < 4; ++kk) {
          const int byte = (row << 8) + ((kk * 32 + lg * 8) << 1);
          bf16x8 kf = *(const bf16x8*)(kc + (byte ^ kx));
          sc[0][c] = __builtin_amdgcn_mfma_f32_16x16x32_bf16(kf, qf[0][kk], sc[0][c], 0, 0, 0);
          sc[1][c] = __builtin_amdgcn_mfma_f32_16x16x32_bf16(kf, qf[1][kk], sc[1][c], 0, 0, 0);
        }
      }
      __builtin_amdgcn_s_setprio(0);

      // ---- masking: only on boundary tiles, per row-block
      const int kbase = s0 + (lg << 2);
#pragma unroll
      for (int rb = 0; rb < 2; ++rb) {
        const int lim_min = t0 + rb * 16 + skv - SQ_;
        if (s0 + 63 > lim_min) {
          const int lim = t0 + rb * 16 + lr + skv - SQ_;
#pragma unroll
          for (int c = 0; c < 4; ++c)
#pragma unroll
            for (int rr = 0; rr < 4; ++rr)
              if (kbase + c * 16 + rr > lim) sc[rb][c][rr] = -1e30f;
        }
      }

      // ---- lane-local max + defer-max (no cross-lane on common path)
      float mx0 = sc[0][0][0], mx1 = sc[1][0][0];
#pragma unroll
      for (int c = 0; c < 4; ++c)
#pragma unroll
        for (int rr = 0; rr < 4; ++rr) {
          mx0 = fmaxf(mx0, sc[0][c][rr]);
          mx1 = fmaxf(mx1, sc[1][c][rr]);
        }
      const float worst = fmaxf(mx0 - m_[0], mx1 - m_[1]);
      if (!__all(worst <= THR_)) {
        float fm[2] = {mx0, mx1};
        float al_[2];
#pragma unroll
        for (int rb = 0; rb < 2; ++rb) {
          float t = fmaxf(fm[rb], __shfl_xor(fm[rb], 16));
          t = fmaxf(t, __shfl_xor(t, 32));
          const float mn = fmaxf(m_[rb], t);
          al_[rb] = exp2_fast(m_[rb] - mn);
          m_[rb] = mn;
          l_[rb] *= al_[rb];
        }
        float alq0[4], alq1[4];
#pragma unroll
        for (int rr = 0; rr < 4; ++rr) {
          alq0[rr] = __shfl(al_[0], lg * 4 + rr, 16);
          alq1[rr] = __shfl(al_[1], lg * 4 + rr, 16);
        }
#pragma unroll
        for (int dd = 0; dd < 8; ++dd)
#pragma unroll
          for (int rr = 0; rr < 4; ++rr) { acc0[dd][rr] *= alq0[rr]; acc1[dd][rr] *= alq1[rr]; }
      }

      // ---- P = 2^(S - m), lane-partial row-sum, packed K=32 A-fragments:
      //      pa8[rb][c2] slot j<4 = key c2*32+4lg+j, slot j>=4 = key c2*32+16+4lg+(j-4)
      bf16x8 pa8[2][2];
#pragma unroll
      for (int rb = 0; rb < 2; ++rb) {
        const float mm = m_[rb];
        float ps = 0.0f;
#pragma unroll
        for (int c = 0; c < 4; ++c) {
          const int c2 = c >> 1, half = (c & 1) * 4;
#pragma unroll
          for (int rr = 0; rr < 4; ++rr) {
            const float pv = exp2_fast(sc[rb][c][rr] - mm);
            ps += pv;
            pa8[rb][c2][half + rr] = (short)cvt_bf16(pv);
          }
        }
        l_[rb] += ps;
      }

      // ---- O += P V: 2 true K=32 MFMAs per (dd, rb)
      __builtin_amdgcn_s_setprio(1);
#pragma unroll
      for (int dd = 0; dd < 8; ++dd) {
        const int d = dd * 16 + lr;
        const int swz = (d & 7) << 4;
#pragma unroll
        for (int c2 = 0; c2 < 2; ++c2) {
          const int base = d * 128 + c2 * 64 + lg * 8;
          bf16x4 vlo = *(const bf16x4*)(vc + (base ^ swz));
          bf16x4 vhi = *(const bf16x4*)(vc + ((base + 32) ^ swz));
          bf16x8 b8 = {vlo[0], vlo[1], vlo[2], vlo[3], vhi[0], vhi[1], vhi[2], vhi[3]};
          acc0[dd] = __builtin_amdgcn_mfma_f32_16x16x32_bf16(pa8[0][c2], b8, acc0[dd], 0, 0, 0);
          acc1[dd] = __builtin_amdgcn_mfma_f32_16x16x32_bf16(pa8[1][c2], b8, acc1[dd], 0, 0, 0);
        }
      }
      __builtin_amdgcn_s_setprio(0);
      asm volatile("" ::: "memory");
      __builtin_amdgcn_s_barrier();
      { char* t = kc; kc = kn; kn = t; t = vc; vc = vn; vn = t; }
    }

    // ---- epilogue: reduce lane-partial l_, normalize / meanv splat
    const float* mp = meanv + ((size_t)(b * HK_ + hk)) * D_;
#pragma unroll
    for (int rb = 0; rb < 2; ++rb) {
      const f32x4* acc = rb ? acc1 : acc0;
      float lsum = l_[rb] + __shfl_xor(l_[rb], 16);
      lsum += __shfl_xor(lsum, 32);
#pragma unroll
      for (int rr = 0; rr < 4; ++rr) {
        const float lq = __shfl(lsum, lg * 4 + rr, 16);
        const int t_r = t0 + rb * 16 + lg * 4 + rr;
        const bool deg = (t_r + skv - SQ_) < 0;
        const float inv = 1.0f / lq;
        float* op = out + (((size_t)b * SQ_ + t_r) * H_ + h) * D_;
#pragma unroll
        for (int dd = 0; dd < 8; ++dd) {
          const int d = dd * 16 + lr;
          op[d] = deg ? mp[d] : acc[dd][rr] * inv;
        }
      }
    }
    __syncthreads();  // all waves done with LDS before next item's broadcast
  }
}

extern "C" void kernel_launch(void* const* d_in, const int* in_sizes, int n_in,
                              void* d_out, int out_size, void* d_ws, size_t ws_size,
                              hipStream_t stream) {
  const float* q = (const float*)d_in[0];
  const float* kv = (const float*)d_in[1];
  const void* mask = d_in[2];
  float* out = (float*)d_out;

  const size_t KB_OFF = 0;
  const size_t VT_OFF = 8ull * 1024 * 1024;
  const size_t MV_OFF = 16ull * 1024 * 1024;
  unsigned short* Kb = (unsigned short*)((char*)d_ws + KB_OFF);
  unsigned short* VTb = (unsigned short*)((char*)d_ws + VT_OFF);
  float* meanv = (float*)((char*)d_ws + MV_OFF);
  int* skv = (int*)((char*)d_ws + MV_OFF + 8192);
  int* work_ctr = (int*)((char*)d_ws + MV_OFF + 8192 + 64);

  hipMemsetAsync((char*)d_ws + MV_OFF, 0, 8192 + 128, stream);
  skv_kernel<<<B_, 256, 0, stream>>>(mask, skv);
  convk<<<dim3(SK_ / 16, HK_, B_), 256, 0, stream>>>(kv, Kb);
  convvt<<<dim3(SK_ / 64, HK_, B_), 256, 0, stream>>>(kv, VTb, meanv);
  flash20<<<dim3(512), 256, 0, stream>>>(q, Kb, VTb, skv, meanv, out, work_ctr);
}

// Round 21
// 147.900 us; speedup vs baseline: 3.9785x; 1.0263x over previous
//
#include <hip/hip_runtime.h>
#include <hip/hip_bf16.h>
#include <cstdint>
#include <cstddef>

constexpr int B_ = 2, SQ_ = 2048, SK_ = 2048, H_ = 32, HK_ = 8, D_ = 128;
constexpr float QSCALE_ = 0.12751874f;           // (1/sqrt(128)) * log2(e)
constexpr float THR_ = 11.5f;                    // 8 nats in log2 units

typedef __attribute__((ext_vector_type(4))) float f32x4;
typedef __attribute__((ext_vector_type(8))) short bf16x8;
typedef __attribute__((ext_vector_type(4))) short bf16x4;

__device__ __forceinline__ unsigned short f2bf(float f) {
  union { float f; uint32_t u; } v; v.f = f;
  uint32_t u = v.u;
  return (unsigned short)((u + 0x7FFFu + ((u >> 16) & 1u)) >> 16);  // RNE
}

__device__ __forceinline__ unsigned short cvt_bf16(float x) {
  __hip_bfloat16 h = __float2bfloat16(x);   // single HW cvt, RNE
  return *reinterpret_cast<unsigned short*>(&h);
}

__device__ __forceinline__ float exp2_fast(float x) {
  float r;
  asm volatile("v_exp_f32 %0, %1" : "=v"(r) : "v"(x));  // v_exp_f32 = 2^x
  return r;
}

__device__ __forceinline__ void gload16(const void* g, void* l) {
  __builtin_amdgcn_global_load_lds((const __attribute__((address_space(1))) void*)g,
                                   (__attribute__((address_space(3))) void*)l, 16, 0, 0);
}

// ---- sk_valid per batch (mask dtype sniffed at runtime)
__global__ void skv_kernel(const void* __restrict__ mask, int* __restrict__ skv_out) {
  const int b = blockIdx.x;
  const int tid = threadIdx.x;
  __shared__ int red[256];
  const uint32_t* mw = (const uint32_t*)mask;
  const uint32_t w0 = mw[0], w1 = mw[1];
  int cnt = 0;
  if (w0 > 1u) {
    const uint8_t* m = (const uint8_t*)mask + (size_t)b * SK_;
    for (int s = tid; s < SK_; s += 256) cnt += (m[s] != 0);
  } else if (w1 == 0u) {
    const uint32_t* m = mw + (size_t)b * SK_ * 2;
    for (int s = tid; s < SK_; s += 256) cnt += (m[2 * s] != 0);
  } else {
    const int* m = (const int*)mask + (size_t)b * SK_;
    for (int s = tid; s < SK_; s += 256) cnt += (m[s] != 0);
  }
  red[tid] = cnt;
  __syncthreads();
  for (int o = 128; o > 0; o >>= 1) {
    if (tid < o) red[tid] += red[tid + o];
    __syncthreads();
  }
  if (tid == 0) skv_out[b] = red[0];
}

// ---- K: f32 [b][s][0][hk][d] -> bf16 Kb [b][hk][s][d]
__global__ void convk(const float* __restrict__ kv, unsigned short* __restrict__ Kb) {
  const int b = blockIdx.z, hk = blockIdx.y;
  const int s = blockIdx.x * 16 + (threadIdx.x >> 4);
  const int dc = (threadIdx.x & 15) * 8;
  const float* src = kv + ((((size_t)b * SK_ + s) * 2 + 0) * HK_ + hk) * D_ + dc;
  f32x4 a0 = *(const f32x4*)src;
  f32x4 a1 = *(const f32x4*)(src + 4);
  bf16x8 t;
  t[0] = (short)f2bf(a0[0]); t[1] = (short)f2bf(a0[1]);
  t[2] = (short)f2bf(a0[2]); t[3] = (short)f2bf(a0[3]);
  t[4] = (short)f2bf(a1[0]); t[5] = (short)f2bf(a1[1]);
  t[6] = (short)f2bf(a1[2]); t[7] = (short)f2bf(a1[3]);
  *(bf16x8*)(Kb + ((size_t)(b * HK_ + hk) * SK_ + s) * D_ + dc) = t;
}

// ---- V: f32 [b][s][1][hk][d] -> bf16 VTb [b][hk][d][s] (transposed),
//      FUSED with meanv accumulation (one atomicAdd per thread).
__global__ void convvt(const float* __restrict__ kv, unsigned short* __restrict__ VTb,
                       float* __restrict__ meanv) {
  const int b = blockIdx.z, hk = blockIdx.y;
  const int s0 = blockIdx.x * 64;
  const int d = threadIdx.x & 127;
  const int sg = threadIdx.x >> 7;
  unsigned short vals[32];
  float vsum = 0.0f;
#pragma unroll
  for (int i = 0; i < 32; ++i) {
    const int s = s0 + sg * 32 + i;
    const float v = kv[((((size_t)b * SK_ + s) * 2 + 1) * HK_ + hk) * D_ + d];
    vsum += v;
    vals[i] = f2bf(v);
  }
  unsigned short* dst = VTb + ((size_t)(b * HK_ + hk) * D_ + d) * SK_ + s0 + sg * 32;
#pragma unroll
  for (int c = 0; c < 4; ++c) {
    bf16x8 t;
#pragma unroll
    for (int i = 0; i < 8; ++i) t[i] = (short)vals[c * 8 + i];
    *(bf16x8*)(dst + c * 8) = t;
  }
  atomicAdd(meanv + ((size_t)b * HK_ + hk) * D_ + d, vsum * (1.0f / (float)SK_));
}

// ---- flash attention v21: r20 (verified best structure) with a single
//      barrier per KV-tile. Schedule per tile j:
//        vmcnt(0)   -> own stage(j) loads drained
//        s_barrier  -> stage(j) visible to all; all waves done compute(j-1)
//        stage(j+1) -> overwrites buffer last read at compute(j-1): safe
//        compute(j)
__global__ __launch_bounds__(256, 2)
void flash21(const float* __restrict__ q, const unsigned short* __restrict__ Kb,
             const unsigned short* __restrict__ VTb, const int* __restrict__ skv_arr,
             const float* __restrict__ meanv, float* __restrict__ out,
             int* __restrict__ work_ctr) {
  const int tid = threadIdx.x;
  const int w = tid >> 6, l = tid & 63, lg = l >> 4, lr = l & 15;

  __shared__ char smem[65536];
  char* kc0 = smem;          char* vc0 = smem + 16384;
  char* kn0 = smem + 32768;  char* vn0 = smem + 49152;

  const int NITEMS = (SQ_ / 32) * HK_ * B_;  // 1024

  for (;;) {
    if (tid == 0) *(volatile int*)smem = atomicAdd(work_ctr, 1);
    __syncthreads();
    const int r = *(volatile int*)smem;
    __syncthreads();
    if (r >= NITEMS) break;

    const int qt = 63 - (r >> 4);   // heaviest first (LPT)
    const int hk = (r >> 1) & 7;
    const int b = r & 1;
    const int h = hk * 4 + w;       // each wave: one q-head of the GQA group
    const int t0 = qt * 32;
    const int skv = skv_arr[b];

    char* kc = kc0; char* kn = kn0; char* vc = vc0; char* vn = vn0;

    // Q B-fragments (swapped QK^T), QSCALE = SCALE*log2e folded in.
    bf16x8 qf[2][4];
#pragma unroll
    for (int rb = 0; rb < 2; ++rb) {
      const int trow = t0 + rb * 16 + lr;
      const float* qp = q + (((size_t)b * SQ_ + trow) * H_ + h) * D_;
#pragma unroll
      for (int kk = 0; kk < 4; ++kk) {
        f32x4 a0 = *(const f32x4*)(qp + kk * 32 + lg * 8);
        f32x4 a1 = *(const f32x4*)(qp + kk * 32 + lg * 8 + 4);
        bf16x8 t;
        t[0] = (short)f2bf(a0[0] * QSCALE_); t[1] = (short)f2bf(a0[1] * QSCALE_);
        t[2] = (short)f2bf(a0[2] * QSCALE_); t[3] = (short)f2bf(a0[3] * QSCALE_);
        t[4] = (short)f2bf(a1[0] * QSCALE_); t[5] = (short)f2bf(a1[1] * QSCALE_);
        t[6] = (short)f2bf(a1[2] * QSCALE_); t[7] = (short)f2bf(a1[3] * QSCALE_);
        qf[rb][kk] = t;
      }
    }

    f32x4 acc0[8], acc1[8];
#pragma unroll
    for (int i = 0; i < 8; ++i) { acc0[i] = (f32x4)0.0f; acc1[i] = (f32x4)0.0f; }
    float m_[2], l_[2];  // m in log2 units; l lane-partial
#pragma unroll
    for (int rb = 0; rb < 2; ++rb) { m_[rb] = -1e30f; l_[rb] = 0.0f; }

    int n_allowed = t0 + 31 + skv - SQ_ + 1;
    if (n_allowed > skv) n_allowed = skv;
    const int nt = (n_allowed > 0) ? ((n_allowed + 63) >> 6) : 0;

    const char* kgb = (const char*)Kb + ((size_t)(b * HK_ + hk)) * SK_ * D_ * 2;
    const char* vgb = (const char*)VTb + ((size_t)(b * HK_ + hk)) * (size_t)D_ * SK_ * 2;

    auto stage = [&](char* kdst, char* vdst, int s0) {
      const char* kt = kgb + (size_t)s0 * 256;
#pragma unroll
      for (int i = 0; i < 4; ++i) {
        const int c8 = w * 4 + i;
        const int beta = c8 * 1024 + l * 16;
        const int row = beta >> 8;
        gload16(kt + (beta ^ ((row & 7) << 4)), kdst + c8 * 1024);
      }
      const char* vt = vgb + (size_t)s0 * 2;
#pragma unroll
      for (int i = 0; i < 4; ++i) {
        const int c8 = w * 4 + i;
        const int beta = c8 * 1024 + l * 16;
        const int lam = beta ^ (((beta >> 7) & 7) << 4);
        const int d = lam >> 7, keyb = lam & 127;
        gload16(vt + (size_t)d * (SK_ * 2) + keyb, vdst + c8 * 1024);
      }
    };

    if (nt > 0) stage(kc, vc, 0);

    for (int j = 0; j < nt; ++j) {
      // own stage(j) loads drained (epilogue stores of prev item also counted; harmless)
      asm volatile("s_waitcnt vmcnt(0)" ::: "memory");
      __builtin_amdgcn_s_barrier();   // stage(j) visible; all waves done compute(j-1)
      if (j + 1 < nt) stage(kn, vn, (j + 1) * 64);  // overwrites compute(j-1)'s buffer

      const int s0 = j * 64;
      // ---- S^T = K Q^T (log2 domain): sc[rb][c][rr]
      f32x4 sc[2][4];
#pragma unroll
      for (int c = 0; c < 4; ++c) { sc[0][c] = (f32x4)0.0f; sc[1][c] = (f32x4)0.0f; }
      __builtin_amdgcn_s_setprio(1);
#pragma unroll
      for (int c = 0; c < 4; ++c) {
        const int row = c * 16 + lr;
        const int kx = (row & 7) << 4;
#pragma unroll
        for (int kk = 0; kk < 4; ++kk) {
          const int byte = (row << 8) + ((kk * 32 + lg * 8) << 1);
          bf16x8 kf = *(const bf16x8*)(kc + (byte ^ kx));
          sc[0][c] = __builtin_amdgcn_mfma_f32_16x16x32_bf16(kf, qf[0][kk], sc[0][c], 0, 0, 0);
          sc[1][c] = __builtin_amdgcn_mfma_f32_16x16x32_bf16(kf, qf[1][kk], sc[1][c], 0, 0, 0);
        }
      }
      __builtin_amdgcn_s_setprio(0);

      // ---- masking: only on boundary tiles, per row-block
      const int kbase = s0 + (lg << 2);
#pragma unroll
      for (int rb = 0; rb < 2; ++rb) {
        const int lim_min = t0 + rb * 16 + skv - SQ_;
        if (s0 + 63 > lim_min) {
          const int lim = t0 + rb * 16 + lr + skv - SQ_;
#pragma unroll
          for (int c = 0; c < 4; ++c)
#pragma unroll
            for (int rr = 0; rr < 4; ++rr)
              if (kbase + c * 16 + rr > lim) sc[rb][c][rr] = -1e30f;
        }
      }

      // ---- lane-local max + defer-max (no cross-lane on common path)
      float mx0 = sc[0][0][0], mx1 = sc[1][0][0];
#pragma unroll
      for (int c = 0; c < 4; ++c)
#pragma unroll
        for (int rr = 0; rr < 4; ++rr) {
          mx0 = fmaxf(mx0, sc[0][c][rr]);
          mx1 = fmaxf(mx1, sc[1][c][rr]);
        }
      const float worst = fmaxf(mx0 - m_[0], mx1 - m_[1]);
      if (!__all(worst <= THR_)) {
        float fm[2] = {mx0, mx1};
        float al_[2];
#pragma unroll
        for (int rb = 0; rb < 2; ++rb) {
          float t = fmaxf(fm[rb], __shfl_xor(fm[rb], 16));
          t = fmaxf(t, __shfl_xor(t, 32));
          const float mn = fmaxf(m_[rb], t);
          al_[rb] = exp2_fast(m_[rb] - mn);
          m_[rb] = mn;
          l_[rb] *= al_[rb];
        }
        float alq0[4], alq1[4];
#pragma unroll
        for (int rr = 0; rr < 4; ++rr) {
          alq0[rr] = __shfl(al_[0], lg * 4 + rr, 16);
          alq1[rr] = __shfl(al_[1], lg * 4 + rr, 16);
        }
#pragma unroll
        for (int dd = 0; dd < 8; ++dd)
#pragma unroll
          for (int rr = 0; rr < 4; ++rr) { acc0[dd][rr] *= alq0[rr]; acc1[dd][rr] *= alq1[rr]; }
      }

      // ---- P = 2^(S - m), lane-partial row-sum, packed K=32 A-fragments
      bf16x8 pa8[2][2];
#pragma unroll
      for (int rb = 0; rb < 2; ++rb) {
        const float mm = m_[rb];
        float ps = 0.0f;
#pragma unroll
        for (int c = 0; c < 4; ++c) {
          const int c2 = c >> 1, half = (c & 1) * 4;
#pragma unroll
          for (int rr = 0; rr < 4; ++rr) {
            const float pv = exp2_fast(sc[rb][c][rr] - mm);
            ps += pv;
            pa8[rb][c2][half + rr] = (short)cvt_bf16(pv);
          }
        }
        l_[rb] += ps;
      }

      // ---- O += P V: 2 true K=32 MFMAs per (dd, rb)
      __builtin_amdgcn_s_setprio(1);
#pragma unroll
      for (int dd = 0; dd < 8; ++dd) {
        const int d = dd * 16 + lr;
        const int swz = (d & 7) << 4;
#pragma unroll
        for (int c2 = 0; c2 < 2; ++c2) {
          const int base = d * 128 + c2 * 64 + lg * 8;
          bf16x4 vlo = *(const bf16x4*)(vc + (base ^ swz));
          bf16x4 vhi = *(const bf16x4*)(vc + ((base + 32) ^ swz));
          bf16x8 b8 = {vlo[0], vlo[1], vlo[2], vlo[3], vhi[0], vhi[1], vhi[2], vhi[3]};
          acc0[dd] = __builtin_amdgcn_mfma_f32_16x16x32_bf16(pa8[0][c2], b8, acc0[dd], 0, 0, 0);
          acc1[dd] = __builtin_amdgcn_mfma_f32_16x16x32_bf16(pa8[1][c2], b8, acc1[dd], 0, 0, 0);
        }
      }
      __builtin_amdgcn_s_setprio(0);
      asm volatile("" ::: "memory");
      { char* t = kc; kc = kn; kn = t; t = vc; vc = vn; vn = t; }
    }

    // ---- epilogue: reduce lane-partial l_, normalize / meanv splat
    const float* mp = meanv + ((size_t)(b * HK_ + hk)) * D_;
#pragma unroll
    for (int rb = 0; rb < 2; ++rb) {
      const f32x4* acc = rb ? acc1 : acc0;
      float lsum = l_[rb] + __shfl_xor(l_[rb], 16);
      lsum += __shfl_xor(lsum, 32);
#pragma unroll
      for (int rr = 0; rr < 4; ++rr) {
        const float lq = __shfl(lsum, lg * 4 + rr, 16);
        const int t_r = t0 + rb * 16 + lg * 4 + rr;
        const bool deg = (t_r + skv - SQ_) < 0;
        const float inv = 1.0f / lq;
        float* op = out + (((size_t)b * SQ_ + t_r) * H_ + h) * D_;
#pragma unroll
        for (int dd = 0; dd < 8; ++dd) {
          const int d = dd * 16 + lr;
          op[d] = deg ? mp[d] : acc[dd][rr] * inv;
        }
      }
    }
    __syncthreads();  // all waves done with LDS before next item's broadcast
  }
}

extern "C" void kernel_launch(void* const* d_in, const int* in_sizes, int n_in,
                              void* d_out, int out_size, void* d_ws, size_t ws_size,
                              hipStream_t stream) {
  const float* q = (const float*)d_in[0];
  const float* kv = (const float*)d_in[1];
  const void* mask = d_in[2];
  float* out = (float*)d_out;

  const size_t KB_OFF = 0;
  const size_t VT_OFF = 8ull * 1024 * 1024;
  const size_t MV_OFF = 16ull * 1024 * 1024;
  unsigned short* Kb = (unsigned short*)((char*)d_ws + KB_OFF);
  unsigned short* VTb = (unsigned short*)((char*)d_ws + VT_OFF);
  float* meanv = (float*)((char*)d_ws + MV_OFF);
  int* skv = (int*)((char*)d_ws + MV_OFF + 8192);
  int* work_ctr = (int*)((char*)d_ws + MV_OFF + 8192 + 64);

  hipMemsetAsync((char*)d_ws + MV_OFF, 0, 8192 + 128, stream);
  skv_kernel<<<B_, 256, 0, stream>>>(mask, skv);
  convk<<<dim3(SK_ / 16, HK_, B_), 256, 0, stream>>>(kv, Kb);
  convvt<<<dim3(SK_ / 64, HK_, B_), 256, 0, stream>>>(kv, VTb, meanv);
  flash21<<<dim3(512), 256, 0, stream>>>(q, Kb, VTb, skv, meanv, out, work_ctr);
}